// Round 4
// baseline (183.483 us; speedup 1.0000x reference)
//
#include <hip/hip_runtime.h>
#include <hip/hip_bf16.h>

#define N_E    500000
#define D_NODE 128
#define D_EDGE 64
#define D_GLOB 64
#define NTILES (N_E / 16)   // 31250 exact
#define TPW    4            // contiguous tiles per wave

typedef __attribute__((ext_vector_type(8))) short s16x8;
typedef __attribute__((ext_vector_type(4))) float fx4;
typedef __attribute__((ext_vector_type(2))) unsigned int u32x2;

__device__ __forceinline__ unsigned short f2bf(float x) {
  union { __hip_bfloat16 h; unsigned short u; } cv;
  cv.h = __float2bfloat16(x);   // RTNE
  return cv.u;
}

// 4 f32 -> 4 bf16 packed in 8 bytes
__device__ __forceinline__ u32x2 cvt4(fx4 v) {
  u32x2 r;
  r[0] = (unsigned)f2bf(v[0]) | ((unsigned)f2bf(v[1]) << 16);
  r[1] = (unsigned)f2bf(v[2]) | ((unsigned)f2bf(v[3]) << 16);
  return r;
}

__global__ __launch_bounds__(256) void edge_mlp_kernel(
    const float* __restrict__ src, const float* __restrict__ dst,
    const float* __restrict__ ea,  const float* __restrict__ u,
    const int*   __restrict__ batch,
    const float* __restrict__ W1,  const float* __restrict__ b1,
    const float* __restrict__ W2,  const float* __restrict__ b2,
    float* __restrict__ out)
{
  // Row strides are odd multiples of 16B -> conflict-free b128 column reads.
  __shared__ unsigned short w1t[32][392];    // W1^T bf16 [n][k], 784B rows
  __shared__ unsigned short w2t[64][40];     // W2^T bf16 [n][k], 80B rows
  __shared__ unsigned short Xs[4][16][392];  // per-wave X tile, bf16 [row][k]
  __shared__ float b1s[32];
  __shared__ float b2s[64];

  const int tid = threadIdx.x;

  for (int i = tid; i < 384 * 32; i += 256) {   // W1 is [384][32] row-major
    int k = i >> 5, n = i & 31;
    w1t[n][k] = f2bf(W1[i]);
  }
  for (int i = tid; i < 32 * 64; i += 256) {    // W2 is [32][64] row-major
    int k = i >> 6, n = i & 63;
    w2t[n][k] = f2bf(W2[i]);
  }
  if (tid < 32) b1s[tid] = b1[tid];
  if (tid < 64) b2s[tid] = b2[tid];
  __syncthreads();

  const int wave = tid >> 6;
  const int lane = tid & 63;
  const int c  = lane & 15;     // A-row / C-col index
  const int r4 = lane >> 4;     // k-group / C-row group
  const int r8 = r4 * 8;
  const int l5  = lane >> 5, l31 = lane & 31;
  const int l4  = lane >> 4, l15 = lane & 15;

  unsigned short (*X)[392] = Xs[wave];
  // H staging aliases the first 1.28KB of this wave's X tile; X data there is
  // dead by the time hl is written (all af ds_reads issue earlier, same-wave
  // DS ops execute in order).
  unsigned short (*hl)[40] = (unsigned short (*)[40])&Xs[wave][0][0];

  const int gw = blockIdx.x * 4 + wave;
  const int t0 = gw * TPW;
  const int t1 = (t0 + TPW < NTILES) ? t0 + TPW : NTILES;
  if (t0 >= NTILES) return;   // after __syncthreads

  const float lam = 1.0507009873554805f;
  const float la  = 1.7580993408473766f;   // lambda*alpha

  for (int tile = t0; tile < t1; ++tile) {
    const int e0 = tile * 16;

    // ---- contiguous global loads: each instr covers 1KB ----
    const char* sb = (const char*)(src + (size_t)e0 * D_NODE);
    const char* db = (const char*)(dst + (size_t)e0 * D_NODE);
    const char* eb = (const char*)(ea  + (size_t)e0 * D_EDGE);

    fx4 vs[8], vd[8], ve[4], vu[4];
#pragma unroll
    for (int i = 0; i < 8; ++i) vs[i] = *(const fx4*)(sb + i * 1024 + lane * 16);
#pragma unroll
    for (int i = 0; i < 8; ++i) vd[i] = *(const fx4*)(db + i * 1024 + lane * 16);
#pragma unroll
    for (int i = 0; i < 4; ++i) ve[i] = *(const fx4*)(eb + i * 1024 + lane * 16);
    int bts[4];
#pragma unroll
    for (int i = 0; i < 4; ++i) bts[i] = batch[e0 + i * 4 + l4];
#pragma unroll
    for (int i = 0; i < 4; ++i)
      vu[i] = *(const fx4*)((const char*)u + (size_t)bts[i] * 256 + l15 * 16);

    // ---- cvt to bf16 + LDS write (b64, ~2-way aliasing max) ----
#pragma unroll
    for (int i = 0; i < 8; ++i) {            // src rows 2i+l5, cols l31*4..+3
      u32x2 p = cvt4(vs[i]);
      *(u32x2*)((char*)&X[2 * i + l5][0] + l31 * 8) = p;
    }
#pragma unroll
    for (int i = 0; i < 8; ++i) {            // dest -> col base 128
      u32x2 p = cvt4(vd[i]);
      *(u32x2*)((char*)&X[2 * i + l5][128] + l31 * 8) = p;
    }
#pragma unroll
    for (int i = 0; i < 4; ++i) {            // ea rows 4i+l4 -> col base 256
      u32x2 p = cvt4(ve[i]);
      *(u32x2*)((char*)&X[4 * i + l4][256] + l15 * 8) = p;
    }
#pragma unroll
    for (int i = 0; i < 4; ++i) {            // u rows 4i+l4 -> col base 320
      u32x2 p = cvt4(vu[i]);
      *(u32x2*)((char*)&X[4 * i + l4][320] + l15 * 8) = p;
    }

    // ---- A-fragments from LDS (conflict-free b128) ----
    s16x8 af[12];
#pragma unroll
    for (int kk = 0; kk < 12; ++kk)
      af[kk] = *(const s16x8*)&X[c][kk * 32 + r8];

    fx4 acc0 = {0.f, 0.f, 0.f, 0.f};
    fx4 acc1 = {0.f, 0.f, 0.f, 0.f};
#pragma unroll
    for (int kk = 0; kk < 12; ++kk) {
      s16x8 bf0 = *(const s16x8*)&w1t[c][kk * 32 + r8];
      s16x8 bf1 = *(const s16x8*)&w1t[c + 16][kk * 32 + r8];
      acc0 = __builtin_amdgcn_mfma_f32_16x16x32_bf16(af[kk], bf0, acc0, 0, 0, 0);
      acc1 = __builtin_amdgcn_mfma_f32_16x16x32_bf16(af[kk], bf1, acc1, 0, 0, 0);
    }

    // bias + SELU, stage H as bf16 for the layout transpose (C->A)
#pragma unroll
    for (int t = 0; t < 2; ++t) {
      const float bb = b1s[c + 16 * t];
      fx4 a = t ? acc1 : acc0;
#pragma unroll
      for (int r = 0; r < 4; ++r) {
        float v = a[r] + bb;
        v = v > 0.f ? lam * v : la * (__expf(v) - 1.f);
        hl[r4 * 4 + r][c + 16 * t] = f2bf(v);
      }
    }

    // Layer 2: one K-step (K=32), 4 N-tiles; bias folded into C-init.
    s16x8 a2 = *(const s16x8*)&hl[c][r8];
    fx4 o0, o1, o2, o3;
    { float bb = b2s[c];      o0 = (fx4){bb, bb, bb, bb}; }
    { float bb = b2s[c + 16]; o1 = (fx4){bb, bb, bb, bb}; }
    { float bb = b2s[c + 32]; o2 = (fx4){bb, bb, bb, bb}; }
    { float bb = b2s[c + 48]; o3 = (fx4){bb, bb, bb, bb}; }
    o0 = __builtin_amdgcn_mfma_f32_16x16x32_bf16(a2, *(const s16x8*)&w2t[c][r8],      o0, 0, 0, 0);
    o1 = __builtin_amdgcn_mfma_f32_16x16x32_bf16(a2, *(const s16x8*)&w2t[c + 16][r8], o1, 0, 0, 0);
    o2 = __builtin_amdgcn_mfma_f32_16x16x32_bf16(a2, *(const s16x8*)&w2t[c + 32][r8], o2, 0, 0, 0);
    o3 = __builtin_amdgcn_mfma_f32_16x16x32_bf16(a2, *(const s16x8*)&w2t[c + 48][r8], o3, 0, 0, 0);

#pragma unroll
    for (int r = 0; r < 4; ++r) {
      float* op = out + (size_t)(e0 + r4 * 4 + r) * 64 + c;
      op[0]  = o0[r];
      op[16] = o1[r];
      op[32] = o2[r];
      op[48] = o3[r];
    }
  }
}

extern "C" void kernel_launch(void* const* d_in, const int* in_sizes, int n_in,
                              void* d_out, int out_size, void* d_ws, size_t ws_size,
                              hipStream_t stream) {
  const float* src   = (const float*)d_in[0];
  const float* dst   = (const float*)d_in[1];
  const float* ea    = (const float*)d_in[2];
  const float* u     = (const float*)d_in[3];
  const int*   batch = (const int*)d_in[4];
  const float* W1    = (const float*)d_in[5];
  const float* b1    = (const float*)d_in[6];
  const float* W2    = (const float*)d_in[7];
  const float* b2    = (const float*)d_in[8];
  float* out = (float*)d_out;

  // ceil(NTILES / TPW) waves, 4 waves per block, contiguous chunk per wave
  const int nwaves  = (NTILES + TPW - 1) / TPW;       // 7813
  const int nblocks = (nwaves + 3) / 4;               // 1954
  hipLaunchKernelGGL(edge_mlp_kernel, dim3(nblocks), dim3(256), 0, stream,
                     src, dst, ea, u, batch, W1, b1, W2, b2, out);
}

// Round 5
// 168.406 us; speedup vs baseline: 1.0895x; 1.0895x over previous
//
#include <hip/hip_runtime.h>
#include <hip/hip_bf16.h>

#define N_E    500000
#define NTILES (N_E / 16)      // 31250
#define NWAVES 768             // 256 blocks x 3 waves
#define BUF_BYTES 24576        // per-tile staged X: src 8K + dest 8K + ea 4K + u 4K
#define WAVE_LDS  (2 * BUF_BYTES)
#define HL_BASE   (3 * WAVE_LDS)          // 147456
#define SMEM_TOTAL (HL_BASE + 3 * 1280)   // 151296 B = 147.75 KiB

typedef __attribute__((ext_vector_type(8))) short s16x8;
typedef __attribute__((ext_vector_type(4))) float fx4;

typedef __attribute__((address_space(1))) const void glb_void;
typedef __attribute__((address_space(3))) void lds_void;

__device__ __forceinline__ unsigned short f2bf(float x) {
  union { __hip_bfloat16 h; unsigned short u; } cv;
  cv.h = __float2bfloat16(x);   // RTNE
  return cv.u;
}

__device__ __forceinline__ s16x8 pack8(fx4 a, fx4 b) {
  s16x8 r;
  r[0] = (short)f2bf(a[0]); r[1] = (short)f2bf(a[1]);
  r[2] = (short)f2bf(a[2]); r[3] = (short)f2bf(a[3]);
  r[4] = (short)f2bf(b[0]); r[5] = (short)f2bf(b[1]);
  r[6] = (short)f2bf(b[2]); r[7] = (short)f2bf(b[3]);
  return r;
}

__device__ __forceinline__ void gl2lds16(const void* g, void* l) {
  __builtin_amdgcn_global_load_lds((glb_void*)g, (lds_void*)l, 16, 0, 0);
}

// Stage one 16-edge tile: 24 x global_load_lds(16B). LDS dest is linear
// (HW: uniform base + lane*16); the XOR-(row&7) swizzle is applied to the
// per-lane GLOBAL source address; ds_reads apply the same XOR (involution).
__device__ __forceinline__ void stage_tile(
    int e0, int lane, int bvals,
    const float* __restrict__ src, const float* __restrict__ dst,
    const float* __restrict__ ea,  const float* __restrict__ u,
    char* bx)
{
#pragma unroll
  for (int i = 0; i < 8; ++i) {              // src: 16 rows x 32 units
    int V = i * 64 + lane;
    int row = V >> 5, w = V & 31;
    int wsw = w ^ (row & 7);
    gl2lds16((const char*)src + (size_t)(e0 + row) * 512 + wsw * 16, bx + i * 1024);
  }
#pragma unroll
  for (int i = 0; i < 8; ++i) {              // dest
    int V = i * 64 + lane;
    int row = V >> 5, w = V & 31;
    int wsw = w ^ (row & 7);
    gl2lds16((const char*)dst + (size_t)(e0 + row) * 512 + wsw * 16, bx + 8192 + i * 1024);
  }
#pragma unroll
  for (int i = 0; i < 4; ++i) {              // ea: 16 rows x 16 units
    int V = i * 64 + lane;
    int row = V >> 4, w = V & 15;
    int wsw = w ^ (row & 7);
    gl2lds16((const char*)ea + (size_t)(e0 + row) * 256 + wsw * 16, bx + 16384 + i * 1024);
  }
#pragma unroll
  for (int i = 0; i < 4; ++i) {              // u[batch]: gathered rows
    int row = i * 4 + (lane >> 4);
    int bt  = __shfl(bvals, row);            // lanes 0..15 hold batch[e0+0..15]
    int w   = lane & 15;
    int wsw = w ^ (row & 7);
    gl2lds16((const char*)u + (size_t)bt * 256 + wsw * 16, bx + 20480 + i * 1024);
  }
}

__global__ __launch_bounds__(192, 1) void edge_mlp_kernel(
    const float* __restrict__ src, const float* __restrict__ dst,
    const float* __restrict__ ea,  const float* __restrict__ u,
    const int*   __restrict__ batch,
    const float* __restrict__ W1,  const float* __restrict__ b1,
    const float* __restrict__ W2,  const float* __restrict__ b2,
    float* __restrict__ out)
{
  __shared__ __align__(1024) char smem[SMEM_TOTAL];

  const int tid  = threadIdx.x;
  const int wave = tid >> 6;
  const int lane = tid & 63;
  const int c  = lane & 15;
  const int r4 = lane >> 4;
  const int r8 = r4 * 8;

  // ---- W1/W2 fragments + biases into REGISTERS (one-time, L2-hot) ----
  s16x8 wf0[12], wf1[12];
#pragma unroll
  for (int kk = 0; kk < 12; ++kk)
#pragma unroll
    for (int j = 0; j < 8; ++j) {
      wf0[kk][j] = (short)f2bf(W1[(kk * 32 + r8 + j) * 32 + c]);
      wf1[kk][j] = (short)f2bf(W1[(kk * 32 + r8 + j) * 32 + c + 16]);
    }
  s16x8 wf2[4];
#pragma unroll
  for (int t = 0; t < 4; ++t)
#pragma unroll
    for (int j = 0; j < 8; ++j)
      wf2[t][j] = (short)f2bf(W2[(r8 + j) * 64 + c + 16 * t]);
  const float bb10 = b1[c], bb11 = b1[c + 16];
  float bb2v[4];
#pragma unroll
  for (int t = 0; t < 4; ++t) bb2v[t] = b2[c + 16 * t];

  // ---- per-wave tile chunk ----
  const int gw = blockIdx.x * 3 + wave;            // 0..767
  const int q = NTILES / NWAVES, rem = NTILES % NWAVES;  // 40, 530
  const int t0 = gw * q + (gw < rem ? gw : rem);
  const int t1 = t0 + q + (gw < rem ? 1 : 0);

  char* x0 = smem + wave * WAVE_LDS;
  char* x1 = x0 + BUF_BYTES;
  unsigned short (*hl)[40] = (unsigned short (*)[40])(smem + HL_BASE + wave * 1280);

  const float lam = 1.0507009873554805f;
  const float la  = 1.7580993408473766f;   // lambda*alpha

  // ---- prologue ----
  int bv_nxt = batch[t0 * 16 + c];                 // for staging t0
  stage_tile(t0 * 16, lane, bv_nxt, src, dst, ea, u, x0);
  {
    const int tn = (t0 + 1 < t1) ? t0 + 1 : t1 - 1;
    bv_nxt = batch[tn * 16 + c];
  }

  char* cur = x0;
  char* nxt = x1;

  for (int t = t0; t < t1; ++t) {
    const int tn = (t + 1 < t1) ? t + 1 : t1 - 1;

    // previous compute's ds_reads all consumed; make it explicit before the
    // async LDS writes of the next stage can land in that buffer.
    __builtin_amdgcn_sched_barrier(0);
    asm volatile("s_waitcnt lgkmcnt(0)" ::: "memory");
    stage_tile(tn * 16, lane, bv_nxt, src, dst, ea, u, nxt);
    __builtin_amdgcn_sched_barrier(0);
    asm volatile("s_waitcnt vmcnt(24)" ::: "memory");  // tile t staged; t+1 in flight
    __builtin_amdgcn_sched_barrier(0);

    // batch values for t+2 (used next iter; load now, far from use)
    const int tn2 = (t + 2 < t1) ? t + 2 : t1 - 1;
    int bv_new = batch[tn2 * 16 + c];

    // ---- A-fragments from swizzled LDS (conflict-free b128) ----
    s16x8 af[12];
#pragma unroll
    for (int kk = 0; kk < 4; ++kk) {
      int u0 = (kk * 8 + r4 * 2)     ^ (c & 7);
      int u1 = (kk * 8 + r4 * 2 + 1) ^ (c & 7);
      fx4 lo = *(const fx4*)(cur + c * 512 + u0 * 16);
      fx4 hi = *(const fx4*)(cur + c * 512 + u1 * 16);
      af[kk] = pack8(lo, hi);
      lo = *(const fx4*)(cur + 8192 + c * 512 + u0 * 16);
      hi = *(const fx4*)(cur + 8192 + c * 512 + u1 * 16);
      af[4 + kk] = pack8(lo, hi);
    }
#pragma unroll
    for (int m = 0; m < 2; ++m) {
      int u0 = (m * 8 + r4 * 2)     ^ (c & 7);
      int u1 = (m * 8 + r4 * 2 + 1) ^ (c & 7);
      fx4 lo = *(const fx4*)(cur + 16384 + c * 256 + u0 * 16);
      fx4 hi = *(const fx4*)(cur + 16384 + c * 256 + u1 * 16);
      af[8 + m] = pack8(lo, hi);
      lo = *(const fx4*)(cur + 20480 + c * 256 + u0 * 16);
      hi = *(const fx4*)(cur + 20480 + c * 256 + u1 * 16);
      af[10 + m] = pack8(lo, hi);
    }

    // ---- layer 1: 24 MFMA ----
    fx4 acc0 = {0.f, 0.f, 0.f, 0.f};
    fx4 acc1 = {0.f, 0.f, 0.f, 0.f};
#pragma unroll
    for (int kk = 0; kk < 12; ++kk) {
      acc0 = __builtin_amdgcn_mfma_f32_16x16x32_bf16(af[kk], wf0[kk], acc0, 0, 0, 0);
      acc1 = __builtin_amdgcn_mfma_f32_16x16x32_bf16(af[kk], wf1[kk], acc1, 0, 0, 0);
    }

    // ---- bias + SELU -> hl (C->A layout transpose through LDS) ----
#pragma unroll
    for (int tt = 0; tt < 2; ++tt) {
      const float bb = tt ? bb11 : bb10;
      fx4 a = tt ? acc1 : acc0;
#pragma unroll
      for (int r = 0; r < 4; ++r) {
        float v = a[r] + bb;
        v = v > 0.f ? lam * v : la * (__expf(v) - 1.f);
        hl[r4 * 4 + r][c + 16 * tt] = f2bf(v);
      }
    }

    // ---- layer 2: K=32, 4 N-tiles, bias in C-init ----
    s16x8 a2 = *(const s16x8*)&hl[c][r8];
    fx4 o0 = {bb2v[0], bb2v[0], bb2v[0], bb2v[0]};
    fx4 o1 = {bb2v[1], bb2v[1], bb2v[1], bb2v[1]};
    fx4 o2 = {bb2v[2], bb2v[2], bb2v[2], bb2v[2]};
    fx4 o3 = {bb2v[3], bb2v[3], bb2v[3], bb2v[3]};
    o0 = __builtin_amdgcn_mfma_f32_16x16x32_bf16(a2, wf2[0], o0, 0, 0, 0);
    o1 = __builtin_amdgcn_mfma_f32_16x16x32_bf16(a2, wf2[1], o1, 0, 0, 0);
    o2 = __builtin_amdgcn_mfma_f32_16x16x32_bf16(a2, wf2[2], o2, 0, 0, 0);
    o3 = __builtin_amdgcn_mfma_f32_16x16x32_bf16(a2, wf2[3], o3, 0, 0, 0);

    const int e0 = t * 16;
#pragma unroll
    for (int r = 0; r < 4; ++r) {
      float* op = out + (size_t)(e0 + r4 * 4 + r) * 64 + c;
      op[0]  = o0[r];
      op[16] = o1[r];
      op[32] = o2[r];
      op[48] = o3[r];
    }

    bv_nxt = bv_new;
    char* tmp = cur; cur = nxt; nxt = tmp;
  }
}

extern "C" void kernel_launch(void* const* d_in, const int* in_sizes, int n_in,
                              void* d_out, int out_size, void* d_ws, size_t ws_size,
                              hipStream_t stream) {
  const float* src   = (const float*)d_in[0];
  const float* dst   = (const float*)d_in[1];
  const float* ea    = (const float*)d_in[2];
  const float* u     = (const float*)d_in[3];
  const int*   batch = (const int*)d_in[4];
  const float* W1    = (const float*)d_in[5];
  const float* b1    = (const float*)d_in[6];
  const float* W2    = (const float*)d_in[7];
  const float* b2    = (const float*)d_in[8];
  float* out = (float*)d_out;

  hipLaunchKernelGGL(edge_mlp_kernel, dim3(256), dim3(192), 0, stream,
                     src, dst, ea, u, batch, W1, b1, W2, b2, out);
}